// Round 4
// baseline (102.959 us; speedup 1.0000x reference)
//
#include <hip/hip_runtime.h>
#include <hip/hip_cooperative_groups.h>

namespace cg = cooperative_groups;

// TcEmbedding: x (B=4, S=4096, D=64) f32.
// norms[b,t] = sum_d |x[b,t,d]|
// tc[b,t]   = t - j, j = nearest index < t with norms[j] < 0.7*(norms[t]+1e-8), else 0.
//
// R4: single cooperative kernel, 1 block per 64-t chunk (256 blocks).
// Phase 1: norms (float4 loads, f64 acc) + chunk min.  grid.sync().
// Phase 2: two-level ballot search; own chunk's norms come from LDS.
// Harness floor: the 268MB d_ws re-poison fill is ~41us/iter of dur_us and
// is not controllable; this round collapses the remaining ~15us of kernel
// time + launch gaps into one ~5us dispatch.

#define DD 64
#define SS 4096

// ---------------- Fused cooperative kernel --------------------------------
__global__ void __launch_bounds__(256)
tc_fused_kernel(const float4* __restrict__ x4, double* __restrict__ nrm,
                double* __restrict__ cmn, float* __restrict__ out) {
    cg::grid_group grid = cg::this_grid();
    __shared__ double sn[64];

    int ci   = blockIdx.x;              // global chunk id = b*64 + c
    int wave = threadIdx.x >> 6;
    int lane = threadIdx.x & 63;

    // ---- Phase 1: 64 L1 norms for this chunk + chunk minimum ----
    int r0 = ci * 64 + wave * 16;       // 16 rows per wave
    #pragma unroll
    for (int k = 0; k < 4; ++k) {
        int rowbase = r0 + k * 4;                 // 4 rows per round
        float4 p = x4[rowbase * 16 + lane];       // 64 lanes x 16B = 4 rows
        double a = (double)fabsf(p.x) + (double)fabsf(p.y) +
                   (double)fabsf(p.z) + (double)fabsf(p.w);
        #pragma unroll
        for (int off = 8; off > 0; off >>= 1)     // 16-lane group reduce
            a += __shfl_xor(a, off, 64);
        if ((lane & 15) == 0) {
            int r = rowbase + (lane >> 4);
            nrm[r] = a;
            sn[r - ci * 64] = a;
        }
    }
    __syncthreads();
    if (threadIdx.x < 64) {
        double m = sn[threadIdx.x];
        #pragma unroll
        for (int off = 32; off > 0; off >>= 1) {
            double o = __shfl_xor(m, off, 64);
            m = (o < m) ? o : m;
        }
        if (threadIdx.x == 0) cmn[ci] = m;
    }
    __threadfence();
    grid.sync();

    // ---- Phase 2: per wave, 16 t's of this chunk via ballot search ----
    int b = ci >> 6;
    int c = ci & 63;
    double v  = sn[lane];                       // own chunk's norms (LDS)
    double cm = cmn[(b << 6) + lane];           // row's chunk minima (L2)

    int cached_cc = -1;
    double v2 = 0.0;
    float myres = 0.0f;
    #pragma unroll 4
    for (int k = 0; k < 16; ++k) {
        int pos = wave * 16 + k;                // t = c*64 + pos
        double thr = 0.7 * (sn[pos] + 1e-8);    // LDS broadcast
        int r = 0;
        // (a) partial current chunk: j in [c*64, t)
        unsigned long long m = __ballot(lane < pos && v < thr);
        if (m) {                                 // wave-uniform branch
            r = pos - (63 - __clzll(m));
        } else {
            // (b) nearest earlier chunk whose min qualifies
            unsigned long long mc = __ballot(lane < c && cm < thr);
            if (mc) {
                int cc = 63 - __clzll(mc);       // wave-uniform
                if (cc != cached_cc) {           // usually stable across k
                    v2 = nrm[(b << 12) + (cc << 6) + lane];
                    cached_cc = cc;
                }
                // (c) nearest element within that chunk (non-empty by cmin)
                unsigned long long m2 = __ballot(v2 < thr);
                r = ((c - cc) << 6) + pos - (63 - __clzll(m2));
            }
        }
        if (lane == k) myres = (float)r;         // lane k keeps t=...+k's answer
    }
    if (lane < 16)
        out[(b << 12) + (c << 6) + wave * 16 + lane] = myres;
}

// ---------------- Fallback path (R3, proven): two kernels ------------------
template <typename T>
__global__ void __launch_bounds__(256)
tc_norms_cmin_kernel(const float4* __restrict__ x4,
                     T* __restrict__ norms, T* __restrict__ cmin) {
    __shared__ T sn[64];
    int ci   = blockIdx.x;
    int wave = threadIdx.x >> 6;
    int lane = threadIdx.x & 63;
    int r0   = ci * 64 + wave * 16;
    #pragma unroll
    for (int k = 0; k < 4; ++k) {
        int rowbase = r0 + k * 4;
        float4 p = x4[rowbase * 16 + lane];
        T a = (T)fabsf(p.x) + (T)fabsf(p.y) + (T)fabsf(p.z) + (T)fabsf(p.w);
        #pragma unroll
        for (int off = 8; off > 0; off >>= 1)
            a += __shfl_xor(a, off, 64);
        if ((lane & 15) == 0) {
            int r = rowbase + (lane >> 4);
            norms[r] = a;
            sn[r - ci * 64] = a;
        }
    }
    __syncthreads();
    if (threadIdx.x < 64) {
        T m = sn[threadIdx.x];
        #pragma unroll
        for (int off = 32; off > 0; off >>= 1) {
            T o = __shfl_xor(m, off, 64);
            m = (o < m) ? o : m;
        }
        if (threadIdx.x == 0) cmin[ci] = m;
    }
}

template <typename T>
__global__ void __launch_bounds__(256)
tc_scan_kernel(const T* __restrict__ norms, const T* __restrict__ cmin,
               float* __restrict__ out) {
    int wave = threadIdx.x >> 6;
    int lane = threadIdx.x & 63;
    int gw   = blockIdx.x * 4 + wave;
    int t0   = gw * 4;
    int b    = t0 >> 12;
    int tr0  = t0 & (SS - 1);
    int c    = tr0 >> 6;
    const T* row = norms + (b << 12);

    T v  = row[(c << 6) + lane];
    T cm = cmin[(b << 6) + lane];

    int cached_cc = -1;
    T v2 = (T)0;
    float res[4];
    #pragma unroll
    for (int k = 0; k < 4; ++k) {
        int tr  = tr0 + k;
        int pos = tr & 63;
        T thr = (T)0.7 * (__shfl(v, pos, 64) + (T)1e-8);
        int r = 0;
        unsigned long long m = __ballot(lane < pos && v < thr);
        if (m) {
            r = tr - ((c << 6) + (63 - __clzll(m)));
        } else {
            unsigned long long mc = __ballot(lane < c && cm < thr);
            if (mc) {
                int cc = 63 - __clzll(mc);
                if (cc != cached_cc) {
                    v2 = row[(cc << 6) + lane];
                    cached_cc = cc;
                }
                unsigned long long m2 = __ballot(v2 < thr);
                r = tr - ((cc << 6) + (63 - __clzll(m2)));
            }
        }
        res[k] = (float)r;
    }
    if (lane == 0) {
        float4 o = make_float4(res[0], res[1], res[2], res[3]);
        ((float4*)out)[gw] = o;
    }
}

extern "C" void kernel_launch(void* const* d_in, const int* in_sizes, int n_in,
                              void* d_out, int out_size, void* d_ws, size_t ws_size,
                              hipStream_t stream) {
    const float4* x4 = (const float4*)d_in[0];
    float* out = (float*)d_out;
    int total  = in_sizes[0];           // B*S*D = 1048576
    int nrows  = total / DD;            // B*S   = 16384
    int nchunk = nrows / 64;            // 256

    double* nrm = (double*)d_ws;
    double* cmn = nrm + nrows;

    // Single fused cooperative kernel (256 blocks x 256 thr, co-resident).
    void* args[] = { (void*)&x4, (void*)&nrm, (void*)&cmn, (void*)&out };
    hipError_t rc = hipLaunchCooperativeKernel(
        (const void*)tc_fused_kernel, dim3(nchunk), dim3(256), args, 0, stream);

    if (rc != hipSuccess) {
        // Fallback: proven R3 two-kernel path (no grid sync needed).
        tc_norms_cmin_kernel<double><<<nchunk, 256, 0, stream>>>(x4, nrm, cmn);
        tc_scan_kernel<double><<<nrows / 16, 256, 0, stream>>>(nrm, cmn, out);
    }
}